// Round 3
// baseline (805.029 us; speedup 1.0000x reference)
//
#include <hip/hip_runtime.h>
#include <hip/hip_fp16.h>

#define NN 100000
#define EE 1200000
#define DD 64
#define CC 40
#define KK 16
#define BSZ 196                          // nodes per sort bucket
#define NBK 512                          // buckets (512*196 = 100352 >= NN)
#define TCAP 3072                        // tmp capacity per bucket (mean 2352, ~15 sigma)
#define EPB 4096                         // edges per phase-A block
#define ABLK ((EE + EPB - 1) / EPB)      // 293

// x layout per state buffer (float4 = 8 halves = 8 channels):
//   P01: [0, 2N)   node n -> {2n, 2n+1};  P23: [2N,4N) same +2N;  P4: [4N,5N) 4N+n
// XCD pinning (block b -> XCD b%8): XCD 0..2 -> planes{0,1} node-thirds,
// 3..5 -> planes{2,3} thirds, 6..7 -> plane{4} halves. Slice/XCD <= 3.2MB.
// All non-gather traffic is non-temporal so the slice owns the L2.
#define NPX 1042                         // slots/XCD: ceil(33334/32)
#define NP4 782                          // ceil(50000/64)
#define GRID8 (8 * NPX)                  // 8336

typedef int   v4i __attribute__((ext_vector_type(4)));
typedef float v4f __attribute__((ext_vector_type(4)));

__device__ __forceinline__ int ntld_i(const int* p) {
    return __builtin_nontemporal_load(p);
}
__device__ __forceinline__ float ntld_f(const float* p) {
    return __builtin_nontemporal_load(p);
}
__device__ __forceinline__ v4i ntld_i4(const int* p) {
    return __builtin_nontemporal_load((const v4i*)p);
}
__device__ __forceinline__ float4 ntld_f4(const float4* p) {
    v4f v = __builtin_nontemporal_load((const v4f*)p);
    return make_float4(v.x, v.y, v.z, v.w);
}
__device__ __forceinline__ void ntst_f4(float4* p, float4 f) {
    v4f v; v.x = f.x; v.y = f.y; v.z = f.z; v.w = f.w;
    __builtin_nontemporal_store(v, (v4f*)p);
}

// ---------- cursor init ----------
__global__ __launch_bounds__(512) void curinit_kernel(int* __restrict__ cursor) {
    int b = threadIdx.x;
    if (b < NBK) cursor[b] = b * TCAP;
}

// ---------- sort phase A: LDS-bin 4096 edges into 512 buckets ----------
__global__ __launch_bounds__(256) void sortA_kernel(const int* __restrict__ src,
                                                    const int* __restrict__ dst,
                                                    int* __restrict__ cursor,
                                                    int2* __restrict__ tmp) {
    __shared__ int2 stg[EPB];                 // 32KB
    __shared__ int hist[NBK], loff[NBK], lcur[NBK], gbase[NBK];  // 8KB
    int t = threadIdx.x;
    long e0 = (long)blockIdx.x * EPB;
    int n = (int)((EE - e0 < EPB) ? (EE - e0) : EPB);
    for (int j = t; j < NBK; j += 256) hist[j] = 0;
    __syncthreads();
    int d[16], sx[16];
#pragma unroll
    for (int j = 0; j < 16; ++j) {
        int i = t + j * 256;
        if (i < n) {
            d[j] = dst[e0 + i];
            sx[j] = src[e0 + i];
            atomicAdd(&hist[d[j] / BSZ], 1);
        } else d[j] = -1;
    }
    __syncthreads();
    int c0 = hist[2 * t], c1 = hist[2 * t + 1];
    int s2 = c0 + c1;
    __syncthreads();
    loff[t] = s2;
    __syncthreads();
    for (int off = 1; off < 256; off <<= 1) {
        int u = (t >= off) ? loff[t - off] : 0;
        __syncthreads();
        loff[t] += u;
        __syncthreads();
    }
    int excl = loff[t] - s2;
    __syncthreads();
    loff[2 * t] = excl;          loff[2 * t + 1] = excl + c0;
    lcur[2 * t] = excl;          lcur[2 * t + 1] = excl + c0;
    gbase[2 * t]     = atomicAdd(&cursor[2 * t], c0);
    gbase[2 * t + 1] = atomicAdd(&cursor[2 * t + 1], c1);
    __syncthreads();
#pragma unroll
    for (int j = 0; j < 16; ++j) {
        if (d[j] >= 0) {
            int b = d[j] / BSZ;
            int p = atomicAdd(&lcur[b], 1);
            stg[p] = make_int2(d[j], sx[j]);
        }
    }
    __syncthreads();
    for (int i = t; i < n; i += 256) {
        int2 r = stg[i];
        int b = r.x / BSZ;
        int pos = gbase[b] + (i - loff[b]);
        if (pos < (b + 1) * TCAP) tmp[pos] = r;  // overflow guard (never hit)
    }
}

// ---------- bucket-base scan ----------
__global__ __launch_bounds__(512) void bscan_kernel(const int* __restrict__ cursor,
                                                    int* __restrict__ bbase,
                                                    int* __restrict__ row_ptr) {
    __shared__ int sm[512];
    int t = threadIdx.x;
    int v = (t < NBK) ? (cursor[t] - t * TCAP) : 0;
    sm[t] = v;
    __syncthreads();
    for (int off = 1; off < 512; off <<= 1) {
        int u = (t >= off) ? sm[t - off] : 0;
        __syncthreads();
        sm[t] += u;
        __syncthreads();
    }
    if (t < NBK) bbase[t] = sm[t] - v;
    if (t == 511) row_ptr[NN] = sm[511];  // == EE
}

// ---------- sort phase B: counting sort within bucket; emit src-only edges ----------
__global__ __launch_bounds__(256) void sortB_kernel(const int2* __restrict__ tmp,
                                                    const int* __restrict__ cursor,
                                                    const int* __restrict__ bbase,
                                                    float* __restrict__ dinv,
                                                    float* __restrict__ sqd,
                                                    int* __restrict__ row_ptr,
                                                    int* __restrict__ er_src) {
    __shared__ int2 se[TCAP];     // 24KB
    __shared__ int so[TCAP];      // 12KB (src only)
    __shared__ int hist[256], lcur[256];
    int b = blockIdx.x;
    int n0 = b * BSZ;
    if (n0 >= NN) return;
    int n1 = n0 + BSZ; if (n1 > NN) n1 = NN;
    int nb = n1 - n0;
    int t = threadIdx.x;
    int cnt = cursor[b] - b * TCAP;
    int base = bbase[b];
    hist[t] = 0;
    __syncthreads();
    for (int i = t; i < cnt; i += 256) {
        int2 r = tmp[b * TCAP + i];
        se[i] = r;
        atomicAdd(&hist[r.x - n0], 1);
    }
    __syncthreads();
    if (t < nb) {
        float dg = (float)(hist[t] + 1);   // +1 self-loop
        dinv[n0 + t] = rsqrtf(dg);
        sqd[n0 + t]  = sqrtf(dg);
    }
    int v = hist[t];
    lcur[t] = v;
    __syncthreads();
    for (int off = 1; off < 256; off <<= 1) {
        int u = (t >= off) ? lcur[t - off] : 0;
        __syncthreads();
        lcur[t] += u;
        __syncthreads();
    }
    int excl = lcur[t] - v;
    __syncthreads();
    lcur[t] = excl;
    if (t < nb) row_ptr[n0 + t] = base + excl;
    __syncthreads();
    for (int i = t; i < cnt; i += 256) {
        int2 r = se[i];
        int ln = r.x - n0;
        int pos = atomicAdd(&lcur[ln], 1);
        so[pos] = r.y;                    // src only (z-space: weights folded out)
    }
    __syncthreads();
    for (int i = t; i < cnt; i += 256) er_src[base + i] = so[i];  // coalesced
}

// ---------- projection: z0 = dinv * (feat @ W^T), stored in P-layout ----------
__global__ __launch_bounds__(256) void proj_kernel(const float4* __restrict__ feat4,
                                                   const float* __restrict__ W,
                                                   const float* __restrict__ dinv,
                                                   float4* __restrict__ z0) {
    __shared__ float smW[CC * 68];   // 10.9KB
    __shared__ float smF[64 * 68];   // 17.4KB
    __shared__ float smO[64 * 42];   // 10.8KB
    int t = threadIdx.x;
    for (int j = t; j < CC * 16; j += 256) {
        int c = j >> 4, q = j & 15;
        *(float4*)(smW + c * 68 + q * 4) = ((const float4*)W)[j];
    }
    int n0 = blockIdx.x * 64;
    for (int j = t; j < 64 * 16; j += 256) {
        int r = j >> 4, q = j & 15;
        if (n0 + r < NN)
            *(float4*)(smF + r * 68 + q * 4) = feat4[(size_t)(n0 + r) * 16 + q];
    }
    __syncthreads();
    int ln = t >> 2, c0 = (t & 3) * 10;
    int node = n0 + ln;
    float acc[10];
#pragma unroll
    for (int c = 0; c < 10; ++c) acc[c] = 0.f;
    if (node < NN) {
#pragma unroll
        for (int db = 0; db < 16; ++db) {
            float4 fv = *(const float4*)(smF + ln * 68 + db * 4);
#pragma unroll
            for (int c = 0; c < 10; ++c) {
                float4 wv = *(const float4*)(smW + (c0 + c) * 68 + db * 4);
                acc[c] = fmaf(fv.x, wv.x, acc[c]);
                acc[c] = fmaf(fv.y, wv.y, acc[c]);
                acc[c] = fmaf(fv.z, wv.z, acc[c]);
                acc[c] = fmaf(fv.w, wv.w, acc[c]);
            }
        }
    }
#pragma unroll
    for (int c = 0; c < 10; ++c) smO[ln * 42 + c0 + c] = acc[c];
    __syncthreads();
    for (int j = t; j < 64 * 5; j += 256) {
        int r = j & 63, q = j >> 6;
        int g = n0 + r;
        if (g < NN) {
            float dv = dinv[g];
            const float* s = smO + r * 42 + q * 8;
            float4 ov;
            __half2* op = (__half2*)&ov;
            op[0] = __floats2half2_rn(dv * s[0], dv * s[1]);
            op[1] = __floats2half2_rn(dv * s[2], dv * s[3]);
            op[2] = __floats2half2_rn(dv * s[4], dv * s[5]);
            op[3] = __floats2half2_rn(dv * s[6], dv * s[7]);
            size_t idx = (q < 2) ? ((size_t)g * 2 + q)
                       : (q < 4) ? ((size_t)2 * NN + (size_t)g * 2 + (q - 2))
                                 : ((size_t)4 * NN + g);
            z0[idx] = ov;
        }
    }
}

// decode float4-of-8-halves into 8 floats
#define DEC8(V, F0, F1, F2, F3)                                             \
    const __half2* hp_##F0 = (const __half2*)&(V);                          \
    float2 F0 = __half22float2(hp_##F0[0]), F1 = __half22float2(hp_##F0[1]);\
    float2 F2 = __half22float2(hp_##F0[2]), F3 = __half22float2(hp_##F0[3]);

#define ACC8U(V)                                                            \
    {                                                                       \
        DEC8(V, f0, f1, f2, f3)                                             \
        a0 += f0.x; a1 += f0.y; a2 += f1.x; a3 += f1.y;                     \
        a4 += f2.x; a5 += f2.y; a6 += f3.x; a7 += f3.y;                     \
    }

// unweighted gather loop; edge indices loaded 4-at-a-time via nt int4
// (4x fewer index lane-requests); gathers stay cacheable (the L2-resident slice).
#define GLOOP(XP, STR, PL)                                                  \
    int e = beg;                                                            \
    {                                                                       \
        int ea = (beg + 3) & ~3;                                            \
        if (ea > end) ea = end;                                             \
        for (; e < ea; ++e) {                                               \
            int s = ntld_i(es + e);                                         \
            float4 v = (XP)[s * (STR) + (PL)];                              \
            ACC8U(v);                                                       \
        }                                                                   \
    }                                                                       \
    int e8 = e + ((end - e) & ~7);                                          \
    for (; e < e8; e += 8) {                                                \
        v4i sA = ntld_i4(es + e);                                           \
        v4i sB = ntld_i4(es + e + 4);                                       \
        float4 v0 = (XP)[sA.x * (STR) + (PL)];                              \
        float4 v1 = (XP)[sA.y * (STR) + (PL)];                              \
        float4 v2 = (XP)[sA.z * (STR) + (PL)];                              \
        float4 v3 = (XP)[sA.w * (STR) + (PL)];                              \
        float4 v4 = (XP)[sB.x * (STR) + (PL)];                              \
        float4 v5 = (XP)[sB.y * (STR) + (PL)];                              \
        float4 v6 = (XP)[sB.z * (STR) + (PL)];                              \
        float4 v7 = (XP)[sB.w * (STR) + (PL)];                              \
        ACC8U(v0); ACC8U(v1); ACC8U(v2); ACC8U(v3);                         \
        ACC8U(v4); ACC8U(v5); ACC8U(v6); ACC8U(v7);                         \
    }                                                                       \
    int e4 = e + ((end - e) & ~3);                                          \
    for (; e < e4; e += 4) {                                                \
        v4i sA = ntld_i4(es + e);                                           \
        float4 v0 = (XP)[sA.x * (STR) + (PL)];                              \
        float4 v1 = (XP)[sA.y * (STR) + (PL)];                              \
        float4 v2 = (XP)[sA.z * (STR) + (PL)];                              \
        float4 v3 = (XP)[sA.w * (STR) + (PL)];                              \
        ACC8U(v0); ACC8U(v1); ACC8U(v2); ACC8U(v3);                         \
    }                                                                       \
    for (; e < end; ++e) {                                                  \
        int s = ntld_i(es + e);                                             \
        float4 v = (XP)[s * (STR) + (PL)];                                  \
        ACC8U(v);                                                           \
    }

// ---------- SpMM propagate body: z_out[d] = dinv[d]^2 * (z[d] + sum z[src]) ----------
template <int STR>
__device__ __forceinline__ void prop_body(
    int g, int pl, size_t off,
    const float4* __restrict__ x, float4* __restrict__ x_out,
    const int* __restrict__ row_ptr, const int* __restrict__ es,
    const float* __restrict__ dinv) {
    const float4* xp = x + off;
    int beg = ntld_i(row_ptr + g), end = ntld_i(row_ptr + g + 1);
    float di = ntld_f(dinv + g);
    float w2 = di * di;
    int sb = g * STR + pl;
    float4 sv = xp[sb];
    float a0, a1, a2, a3, a4, a5, a6, a7;
    {
        DEC8(sv, f0, f1, f2, f3)
        a0 = f0.x; a1 = f0.y; a2 = f1.x; a3 = f1.y;
        a4 = f2.x; a5 = f2.y; a6 = f3.x; a7 = f3.y;
    }
    GLOOP(xp, STR, pl)
    float4 ov;
    __half2* op = (__half2*)&ov;
    op[0] = __floats2half2_rn(w2 * a0, w2 * a1);
    op[1] = __floats2half2_rn(w2 * a2, w2 * a3);
    op[2] = __floats2half2_rn(w2 * a4, w2 * a5);
    op[3] = __floats2half2_rn(w2 * a6, w2 * a7);
    ntst_f4(x_out + off + sb, ov);
}

// block -> (work). XCD k = blockIdx%8.
__global__ __launch_bounds__(64) void spmm_prop(
    const float4* __restrict__ x, float4* __restrict__ x_out,
    const int* __restrict__ row_ptr, const int* __restrict__ es,
    const float* __restrict__ dinv) {
    int xcd = blockIdx.x & 7;
    int slot = blockIdx.x >> 3;
    int lane = threadIdx.x;
    if (xcd < 6) {
        int part = (xcd < 3) ? xcd : xcd - 3;
        int grp  = (xcd < 3) ? 0 : 1;
        int b0 = (part == 0) ? 0 : ((part == 1) ? 33334 : 66667);
        int b1 = (part == 0) ? 33334 : ((part == 1) ? 66667 : 100000);
        int g = b0 + slot * 32 + (lane >> 1);
        if (g >= b1) return;
        prop_body<2>(g, lane & 1, (size_t)grp * 2 * NN, x, x_out, row_ptr, es, dinv);
    } else {
        if (slot >= NP4) return;
        int b0 = (xcd - 6) * 50000;
        int g = b0 + slot * 64 + lane;
        if (g >= b0 + 50000) return;
        prop_body<1>(g, 0, (size_t)4 * NN, x, x_out, row_ptr, es, dinv);
    }
}

// ---------- final: acc = sum z15 (incl self); out = C16*dinv*acc
//            + sqd*(C15*z15 + C14*z14 + C13*z13 + FC*z0) + bias ----------
template <int STR>
__device__ __forceinline__ void final_body(
    int g, int pl, int p, size_t off,
    const float4* __restrict__ x15, const float4* __restrict__ x13p,
    const float4* __restrict__ x14p, const float4* __restrict__ z0p,
    const float* __restrict__ bias,
    const int* __restrict__ row_ptr, const int* __restrict__ es,
    const float* __restrict__ dinv, const float* __restrict__ sqd,
    float* __restrict__ outp) {
    const float4* xp = x15 + off;
    int beg = ntld_i(row_ptr + g), end = ntld_i(row_ptr + g + 1);
    float di = ntld_f(dinv + g);
    float sq = ntld_f(sqd + g);
    int sb = g * STR + pl;
    size_t gi = off + sb;
    float4 sv = xp[sb];
    float s0, s1, s2, s3, s4, s5, s6, s7;
    float a0, a1, a2, a3, a4, a5, a6, a7;
    {
        DEC8(sv, f0, f1, f2, f3)
        s0 = f0.x; s1 = f0.y; s2 = f1.x; s3 = f1.y;
        s4 = f2.x; s5 = f2.y; s6 = f3.x; s7 = f3.y;
        a0 = s0; a1 = s1; a2 = s2; a3 = s3;
        a4 = s4; a5 = s5; a6 = s6; a7 = s7;
    }
    GLOOP(xp, STR, pl)
    const float C16 = 0.95f / 16.0f;
    const float C15 = 0.95f / 256.0f;
    const float C14 = 0.95f / 4096.0f;
    const float C13 = 0.95f / 65536.0f;
    const float FC  = 0.05f / 15.0f;
    float t0 = C15 * s0, t1 = C15 * s1, t2 = C15 * s2, t3 = C15 * s3;
    float t4 = C15 * s4, t5 = C15 * s5, t6 = C15 * s6, t7 = C15 * s7;
#define ADD8T(P, CF)                                                        \
    {                                                                       \
        float4 v = ntld_f4((P) + gi);                                       \
        DEC8(v, f0, f1, f2, f3)                                             \
        t0 = fmaf((CF), f0.x, t0); t1 = fmaf((CF), f0.y, t1);               \
        t2 = fmaf((CF), f1.x, t2); t3 = fmaf((CF), f1.y, t3);               \
        t4 = fmaf((CF), f2.x, t4); t5 = fmaf((CF), f2.y, t5);               \
        t6 = fmaf((CF), f3.x, t6); t7 = fmaf((CF), f3.y, t7);               \
    }
    ADD8T(x14p, C14)
    ADD8T(x13p, C13)
    ADD8T(z0p, FC)
#undef ADD8T
    float cd = C16 * di;
    float o0 = fmaf(sq, t0, cd * a0), o1 = fmaf(sq, t1, cd * a1);
    float o2 = fmaf(sq, t2, cd * a2), o3 = fmaf(sq, t3, cd * a3);
    float o4 = fmaf(sq, t4, cd * a4), o5 = fmaf(sq, t5, cd * a5);
    float o6 = fmaf(sq, t6, cd * a6), o7 = fmaf(sq, t7, cd * a7);
    const float4* b4 = (const float4*)(bias + p * 8);
    float4 bb0 = b4[0], bb1 = b4[1];
    float4* op = (float4*)(outp + (size_t)g * CC + p * 8);
    ntst_f4(op,     make_float4(o0 + bb0.x, o1 + bb0.y, o2 + bb0.z, o3 + bb0.w));
    ntst_f4(op + 1, make_float4(o4 + bb1.x, o5 + bb1.y, o6 + bb1.z, o7 + bb1.w));
}

__global__ __launch_bounds__(64) void spmm_final(
    const float4* __restrict__ x15, const float4* __restrict__ x13p,
    const float4* __restrict__ x14p, const float4* __restrict__ z0p,
    const float* __restrict__ bias,
    const int* __restrict__ row_ptr, const int* __restrict__ es,
    const float* __restrict__ dinv, const float* __restrict__ sqd,
    float* __restrict__ outp) {
    int xcd = blockIdx.x & 7;
    int slot = blockIdx.x >> 3;
    int lane = threadIdx.x;
    if (xcd < 6) {
        int part = (xcd < 3) ? xcd : xcd - 3;
        int grp  = (xcd < 3) ? 0 : 1;
        int b0 = (part == 0) ? 0 : ((part == 1) ? 33334 : 66667);
        int b1 = (part == 0) ? 33334 : ((part == 1) ? 66667 : 100000);
        int g = b0 + slot * 32 + (lane >> 1);
        if (g >= b1) return;
        int pl = lane & 1;
        final_body<2>(g, pl, grp * 2 + pl, (size_t)grp * 2 * NN,
                      x15, x13p, x14p, z0p, bias, row_ptr, es, dinv, sqd, outp);
    } else {
        if (slot >= NP4) return;
        int b0 = (xcd - 6) * 50000;
        int g = b0 + slot * 64 + lane;
        if (g >= b0 + 50000) return;
        final_body<1>(g, 0, 4, (size_t)4 * NN,
                      x15, x13p, x14p, z0p, bias, row_ptr, es, dinv, sqd, outp);
    }
}

extern "C" void kernel_launch(void* const* d_in, const int* in_sizes, int n_in,
                              void* d_out, int out_size, void* d_ws, size_t ws_size,
                              hipStream_t stream) {
    const float* feat = (const float*)d_in[0];
    const float* W    = (const float*)d_in[1];
    const float* b    = (const float*)d_in[2];
    const int*   src  = (const int*)d_in[3];
    const int*   dst  = (const int*)d_in[4];
    float* out = (float*)d_out;

    char* p = (char*)d_ws;
    auto alloc = [&](size_t bytes) {
        char* r = p;
        p += (bytes + 255) & ~(size_t)255;
        return r;
    };
    float*   dinv    = (float*)alloc((size_t)NN * sizeof(float));
    float*   sqd     = (float*)alloc((size_t)NN * sizeof(float));
    int*     row_ptr = (int*)alloc((size_t)(NN + 1) * sizeof(int));
    int*     cursor  = (int*)alloc((size_t)NBK * sizeof(int));
    int*     bbase   = (int*)alloc((size_t)NBK * sizeof(int));
    int2*    tmp     = (int2*)alloc((size_t)NBK * TCAP * sizeof(int2));  // 12.6MB
    int*     er_src  = (int*)alloc((size_t)EE * sizeof(int));            // 4.8MB
    float4*  z0      = (float4*)alloc((size_t)NN * 5 * sizeof(float4));  // 8MB
    float4*  xa      = (float4*)alloc((size_t)NN * 5 * sizeof(float4));  // 8MB
    float4*  xb      = (float4*)alloc((size_t)NN * 5 * sizeof(float4));  // 8MB
    float4*  z13     = (float4*)alloc((size_t)NN * 5 * sizeof(float4));  // 8MB
    float4*  z14     = (float4*)alloc((size_t)NN * 5 * sizeof(float4));  // 8MB
    float4*  z15     = (float4*)alloc((size_t)NN * 5 * sizeof(float4));  // 8MB

    curinit_kernel<<<1, 512, 0, stream>>>(cursor);
    sortA_kernel<<<ABLK, 256, 0, stream>>>(src, dst, cursor, tmp);
    bscan_kernel<<<1, 512, 0, stream>>>(cursor, bbase, row_ptr);
    sortB_kernel<<<NBK, 256, 0, stream>>>(tmp, cursor, bbase, dinv, sqd, row_ptr, er_src);
    proj_kernel<<<(NN + 63) / 64, 256, 0, stream>>>((const float4*)feat, W, dinv, z0);

    // z1..z12: ping-pong xa/xb
    const float4* xs = z0;
    for (int j = 0; j < 12; ++j) {
        float4* xd = (j & 1) ? xb : xa;
        spmm_prop<<<GRID8, 64, 0, stream>>>(xs, xd, row_ptr, er_src, dinv);
        xs = xd;
    }
    // z13, z14, z15 into preserved buffers
    spmm_prop<<<GRID8, 64, 0, stream>>>(xs, z13, row_ptr, er_src, dinv);
    spmm_prop<<<GRID8, 64, 0, stream>>>(z13, z14, row_ptr, er_src, dinv);
    spmm_prop<<<GRID8, 64, 0, stream>>>(z14, z15, row_ptr, er_src, dinv);
    // final combine
    spmm_final<<<GRID8, 64, 0, stream>>>(z15, z13, z14, z0, b, row_ptr,
                                         er_src, dinv, sqd, out);
}

// Round 4
// 597.797 us; speedup vs baseline: 1.3467x; 1.3467x over previous
//
#include <hip/hip_runtime.h>
#include <hip/hip_fp16.h>

#define NN 100000
#define EE 1200000
#define DD 64
#define CC 40
#define KK 16
#define BSZ 196                          // nodes per sort bucket
#define NBK 512                          // buckets (512*196 = 100352 >= NN)
#define TCAP 3072                        // tmp capacity per bucket (mean 2352, ~15 sigma)
#define EPB 4096                         // edges per phase-A block
#define ABLK ((EE + EPB - 1) / EPB)      // 293

// x layout per state buffer (float4 = 8 halves = 8 channels):
//   P01: [0, 2N)   node n -> {2n, 2n+1};  P23: [2N,4N) same +2N;  P4: [4N,5N) 4N+n
// XCD pinning (block b -> XCD b%8): XCD 0..2 -> planes{0,1} node-thirds,
// 3..5 -> planes{2,3} thirds, 6..7 -> plane{4} halves. Slice/XCD <= 3.2MB.
// Normal (cached) stores keep each XCD's slice in its own L2 across steps
// (producer CU and consumer CU are on the same XCD). NO nt anywhere —
// round-3 showed nt on index/row loads adds critical-path latency (+15us).
#define SLT 261                          // slots/XCD: ceil(33334/128)
#define SLT4 196                         // ceil(50000/256)
#define GRID8 (8 * SLT)                  // 2088 blocks of 256 threads

typedef int v4i __attribute__((ext_vector_type(4)));

// ---------- cursor init ----------
__global__ __launch_bounds__(512) void curinit_kernel(int* __restrict__ cursor) {
    int b = threadIdx.x;
    if (b < NBK) cursor[b] = b * TCAP;
}

// ---------- sort phase A: LDS-bin 4096 edges into 512 buckets ----------
__global__ __launch_bounds__(256) void sortA_kernel(const int* __restrict__ src,
                                                    const int* __restrict__ dst,
                                                    int* __restrict__ cursor,
                                                    int2* __restrict__ tmp) {
    __shared__ int2 stg[EPB];                 // 32KB
    __shared__ int hist[NBK], loff[NBK], lcur[NBK], gbase[NBK];  // 8KB
    int t = threadIdx.x;
    long e0 = (long)blockIdx.x * EPB;
    int n = (int)((EE - e0 < EPB) ? (EE - e0) : EPB);
    for (int j = t; j < NBK; j += 256) hist[j] = 0;
    __syncthreads();
    int d[16], sx[16];
#pragma unroll
    for (int j = 0; j < 16; ++j) {
        int i = t + j * 256;
        if (i < n) {
            d[j] = dst[e0 + i];
            sx[j] = src[e0 + i];
            atomicAdd(&hist[d[j] / BSZ], 1);
        } else d[j] = -1;
    }
    __syncthreads();
    int c0 = hist[2 * t], c1 = hist[2 * t + 1];
    int s2 = c0 + c1;
    __syncthreads();
    loff[t] = s2;
    __syncthreads();
    for (int off = 1; off < 256; off <<= 1) {
        int u = (t >= off) ? loff[t - off] : 0;
        __syncthreads();
        loff[t] += u;
        __syncthreads();
    }
    int excl = loff[t] - s2;
    __syncthreads();
    loff[2 * t] = excl;          loff[2 * t + 1] = excl + c0;
    lcur[2 * t] = excl;          lcur[2 * t + 1] = excl + c0;
    gbase[2 * t]     = atomicAdd(&cursor[2 * t], c0);
    gbase[2 * t + 1] = atomicAdd(&cursor[2 * t + 1], c1);
    __syncthreads();
#pragma unroll
    for (int j = 0; j < 16; ++j) {
        if (d[j] >= 0) {
            int b = d[j] / BSZ;
            int p = atomicAdd(&lcur[b], 1);
            stg[p] = make_int2(d[j], sx[j]);
        }
    }
    __syncthreads();
    for (int i = t; i < n; i += 256) {
        int2 r = stg[i];
        int b = r.x / BSZ;
        int pos = gbase[b] + (i - loff[b]);
        if (pos < (b + 1) * TCAP) tmp[pos] = r;  // overflow guard (never hit)
    }
}

// ---------- bucket-base scan ----------
__global__ __launch_bounds__(512) void bscan_kernel(const int* __restrict__ cursor,
                                                    int* __restrict__ bbase,
                                                    int* __restrict__ row_ptr) {
    __shared__ int sm[512];
    int t = threadIdx.x;
    int v = (t < NBK) ? (cursor[t] - t * TCAP) : 0;
    sm[t] = v;
    __syncthreads();
    for (int off = 1; off < 512; off <<= 1) {
        int u = (t >= off) ? sm[t - off] : 0;
        __syncthreads();
        sm[t] += u;
        __syncthreads();
    }
    if (t < NBK) bbase[t] = sm[t] - v;
    if (t == 511) row_ptr[NN] = sm[511];  // == EE
}

// ---------- sort phase B: counting sort within bucket; emit src-only edges ----------
__global__ __launch_bounds__(256) void sortB_kernel(const int2* __restrict__ tmp,
                                                    const int* __restrict__ cursor,
                                                    const int* __restrict__ bbase,
                                                    float* __restrict__ dinv,
                                                    float* __restrict__ sqd,
                                                    int* __restrict__ row_ptr,
                                                    int* __restrict__ er_src) {
    __shared__ int2 se[TCAP];     // 24KB
    __shared__ int so[TCAP];      // 12KB (src only)
    __shared__ int hist[256], lcur[256];
    int b = blockIdx.x;
    int n0 = b * BSZ;
    if (n0 >= NN) return;
    int n1 = n0 + BSZ; if (n1 > NN) n1 = NN;
    int nb = n1 - n0;
    int t = threadIdx.x;
    int cnt = cursor[b] - b * TCAP;
    int base = bbase[b];
    hist[t] = 0;
    __syncthreads();
    for (int i = t; i < cnt; i += 256) {
        int2 r = tmp[b * TCAP + i];
        se[i] = r;
        atomicAdd(&hist[r.x - n0], 1);
    }
    __syncthreads();
    if (t < nb) {
        float dg = (float)(hist[t] + 1);   // +1 self-loop
        dinv[n0 + t] = rsqrtf(dg);
        sqd[n0 + t]  = sqrtf(dg);
    }
    int v = hist[t];
    lcur[t] = v;
    __syncthreads();
    for (int off = 1; off < 256; off <<= 1) {
        int u = (t >= off) ? lcur[t - off] : 0;
        __syncthreads();
        lcur[t] += u;
        __syncthreads();
    }
    int excl = lcur[t] - v;
    __syncthreads();
    lcur[t] = excl;
    if (t < nb) row_ptr[n0 + t] = base + excl;
    __syncthreads();
    for (int i = t; i < cnt; i += 256) {
        int2 r = se[i];
        int ln = r.x - n0;
        int pos = atomicAdd(&lcur[ln], 1);
        so[pos] = r.y;                    // src only (z-space: weights folded out)
    }
    __syncthreads();
    for (int i = t; i < cnt; i += 256) er_src[base + i] = so[i];  // coalesced
}

// ---------- projection: z0 = dinv * (feat @ W^T), stored in P-layout ----------
__global__ __launch_bounds__(256) void proj_kernel(const float4* __restrict__ feat4,
                                                   const float* __restrict__ W,
                                                   const float* __restrict__ dinv,
                                                   float4* __restrict__ z0) {
    __shared__ float smW[CC * 68];   // 10.9KB
    __shared__ float smF[64 * 68];   // 17.4KB
    __shared__ float smO[64 * 42];   // 10.8KB
    int t = threadIdx.x;
    for (int j = t; j < CC * 16; j += 256) {
        int c = j >> 4, q = j & 15;
        *(float4*)(smW + c * 68 + q * 4) = ((const float4*)W)[j];
    }
    int n0 = blockIdx.x * 64;
    for (int j = t; j < 64 * 16; j += 256) {
        int r = j >> 4, q = j & 15;
        if (n0 + r < NN)
            *(float4*)(smF + r * 68 + q * 4) = feat4[(size_t)(n0 + r) * 16 + q];
    }
    __syncthreads();
    int ln = t >> 2, c0 = (t & 3) * 10;
    int node = n0 + ln;
    float acc[10];
#pragma unroll
    for (int c = 0; c < 10; ++c) acc[c] = 0.f;
    if (node < NN) {
#pragma unroll
        for (int db = 0; db < 16; ++db) {
            float4 fv = *(const float4*)(smF + ln * 68 + db * 4);
#pragma unroll
            for (int c = 0; c < 10; ++c) {
                float4 wv = *(const float4*)(smW + (c0 + c) * 68 + db * 4);
                acc[c] = fmaf(fv.x, wv.x, acc[c]);
                acc[c] = fmaf(fv.y, wv.y, acc[c]);
                acc[c] = fmaf(fv.z, wv.z, acc[c]);
                acc[c] = fmaf(fv.w, wv.w, acc[c]);
            }
        }
    }
#pragma unroll
    for (int c = 0; c < 10; ++c) smO[ln * 42 + c0 + c] = acc[c];
    __syncthreads();
    for (int j = t; j < 64 * 5; j += 256) {
        int r = j & 63, q = j >> 6;
        int g = n0 + r;
        if (g < NN) {
            float dv = dinv[g];
            const float* s = smO + r * 42 + q * 8;
            float4 ov;
            __half2* op = (__half2*)&ov;
            op[0] = __floats2half2_rn(dv * s[0], dv * s[1]);
            op[1] = __floats2half2_rn(dv * s[2], dv * s[3]);
            op[2] = __floats2half2_rn(dv * s[4], dv * s[5]);
            op[3] = __floats2half2_rn(dv * s[6], dv * s[7]);
            size_t idx = (q < 2) ? ((size_t)g * 2 + q)
                       : (q < 4) ? ((size_t)2 * NN + (size_t)g * 2 + (q - 2))
                                 : ((size_t)4 * NN + g);
            z0[idx] = ov;
        }
    }
}

// decode float4-of-8-halves into 8 floats
#define DEC8(V, F0, F1, F2, F3)                                             \
    const __half2* hp_##F0 = (const __half2*)&(V);                          \
    float2 F0 = __half22float2(hp_##F0[0]), F1 = __half22float2(hp_##F0[1]);\
    float2 F2 = __half22float2(hp_##F0[2]), F3 = __half22float2(hp_##F0[3]);

#define ACC8U(V)                                                            \
    {                                                                       \
        DEC8(V, f0, f1, f2, f3)                                             \
        a0 += f0.x; a1 += f0.y; a2 += f1.x; a3 += f1.y;                     \
        a4 += f2.x; a5 += f2.y; a6 += f3.x; a7 += f3.y;                     \
    }

// unweighted gather loop; edge indices loaded 4-at-a-time via CACHED int4
// (4x fewer index instrs; sibling lanes of a node re-read the same 16B -> L1 hits).
#define GLOOP(XP, STR, PL)                                                  \
    int e = beg;                                                            \
    {                                                                       \
        int ea = (beg + 3) & ~3;                                            \
        if (ea > end) ea = end;                                             \
        for (; e < ea; ++e) {                                               \
            int s = es[e];                                                  \
            float4 v = (XP)[s * (STR) + (PL)];                              \
            ACC8U(v);                                                       \
        }                                                                   \
    }                                                                       \
    int e8 = e + ((end - e) & ~7);                                          \
    for (; e < e8; e += 8) {                                                \
        v4i sA = *(const v4i*)(es + e);                                     \
        v4i sB = *(const v4i*)(es + e + 4);                                 \
        float4 v0 = (XP)[sA.x * (STR) + (PL)];                              \
        float4 v1 = (XP)[sA.y * (STR) + (PL)];                              \
        float4 v2 = (XP)[sA.z * (STR) + (PL)];                              \
        float4 v3 = (XP)[sA.w * (STR) + (PL)];                              \
        float4 v4 = (XP)[sB.x * (STR) + (PL)];                              \
        float4 v5 = (XP)[sB.y * (STR) + (PL)];                              \
        float4 v6 = (XP)[sB.z * (STR) + (PL)];                              \
        float4 v7 = (XP)[sB.w * (STR) + (PL)];                              \
        ACC8U(v0); ACC8U(v1); ACC8U(v2); ACC8U(v3);                         \
        ACC8U(v4); ACC8U(v5); ACC8U(v6); ACC8U(v7);                         \
    }                                                                       \
    int e4 = e + ((end - e) & ~3);                                          \
    for (; e < e4; e += 4) {                                                \
        v4i sA = *(const v4i*)(es + e);                                     \
        float4 v0 = (XP)[sA.x * (STR) + (PL)];                              \
        float4 v1 = (XP)[sA.y * (STR) + (PL)];                              \
        float4 v2 = (XP)[sA.z * (STR) + (PL)];                              \
        float4 v3 = (XP)[sA.w * (STR) + (PL)];                              \
        ACC8U(v0); ACC8U(v1); ACC8U(v2); ACC8U(v3);                         \
    }                                                                       \
    for (; e < end; ++e) {                                                  \
        int s = es[e];                                                      \
        float4 v = (XP)[s * (STR) + (PL)];                                  \
        ACC8U(v);                                                           \
    }

// ---------- SpMM propagate body: z_out[d] = dinv[d]^2 * (z[d] + sum z[src]) ----------
template <int STR>
__device__ __forceinline__ void prop_body(
    int g, int pl, size_t off,
    const float4* __restrict__ x, float4* __restrict__ x_out,
    const int* __restrict__ row_ptr, const int* __restrict__ es,
    const float* __restrict__ dinv) {
    const float4* xp = x + off;
    int beg = row_ptr[g], end = row_ptr[g + 1];
    float di = dinv[g];
    float w2 = di * di;
    int sb = g * STR + pl;
    float4 sv = xp[sb];
    float a0, a1, a2, a3, a4, a5, a6, a7;
    {
        DEC8(sv, f0, f1, f2, f3)
        a0 = f0.x; a1 = f0.y; a2 = f1.x; a3 = f1.y;
        a4 = f2.x; a5 = f2.y; a6 = f3.x; a7 = f3.y;
    }
    GLOOP(xp, STR, pl)
    float4 ov;
    __half2* op = (__half2*)&ov;
    op[0] = __floats2half2_rn(w2 * a0, w2 * a1);
    op[1] = __floats2half2_rn(w2 * a2, w2 * a3);
    op[2] = __floats2half2_rn(w2 * a4, w2 * a5);
    op[3] = __floats2half2_rn(w2 * a6, w2 * a7);
    x_out[off + sb] = ov;   // normal store: allocates in this XCD's L2 for next step
}

// 256-thread blocks (4 waves) for latency hiding; XCD k = blockIdx%8.
__global__ __launch_bounds__(256) void spmm_prop(
    const float4* __restrict__ x, float4* __restrict__ x_out,
    const int* __restrict__ row_ptr, const int* __restrict__ es,
    const float* __restrict__ dinv) {
    int xcd = blockIdx.x & 7;
    int slot = blockIdx.x >> 3;
    int t = threadIdx.x;
    if (xcd < 6) {
        int part = (xcd < 3) ? xcd : xcd - 3;
        int grp  = (xcd < 3) ? 0 : 1;
        int b0 = (part == 0) ? 0 : ((part == 1) ? 33334 : 66667);
        int b1 = (part == 0) ? 33334 : ((part == 1) ? 66667 : 100000);
        int g = b0 + slot * 128 + (t >> 1);
        if (g >= b1) return;
        prop_body<2>(g, t & 1, (size_t)grp * 2 * NN, x, x_out, row_ptr, es, dinv);
    } else {
        if (slot >= SLT4) return;
        int b0 = (xcd - 6) * 50000;
        int g = b0 + slot * 256 + t;
        if (g >= b0 + 50000) return;
        prop_body<1>(g, 0, (size_t)4 * NN, x, x_out, row_ptr, es, dinv);
    }
}

// ---------- final: acc = sum z15 (incl self); out = C16*dinv*acc
//            + sqd*(C15*z15 + C14*z14 + C13*z13 + FC*z0) + bias ----------
template <int STR>
__device__ __forceinline__ void final_body(
    int g, int pl, int p, size_t off,
    const float4* __restrict__ x15, const float4* __restrict__ x13p,
    const float4* __restrict__ x14p, const float4* __restrict__ z0p,
    const float* __restrict__ bias,
    const int* __restrict__ row_ptr, const int* __restrict__ es,
    const float* __restrict__ dinv, const float* __restrict__ sqd,
    float* __restrict__ outp) {
    const float4* xp = x15 + off;
    int beg = row_ptr[g], end = row_ptr[g + 1];
    float di = dinv[g];
    float sq = sqd[g];
    int sb = g * STR + pl;
    size_t gi = off + sb;
    float4 sv = xp[sb];
    float s0, s1, s2, s3, s4, s5, s6, s7;
    float a0, a1, a2, a3, a4, a5, a6, a7;
    {
        DEC8(sv, f0, f1, f2, f3)
        s0 = f0.x; s1 = f0.y; s2 = f1.x; s3 = f1.y;
        s4 = f2.x; s5 = f2.y; s6 = f3.x; s7 = f3.y;
        a0 = s0; a1 = s1; a2 = s2; a3 = s3;
        a4 = s4; a5 = s5; a6 = s6; a7 = s7;
    }
    GLOOP(xp, STR, pl)
    const float C16 = 0.95f / 16.0f;
    const float C15 = 0.95f / 256.0f;
    const float C14 = 0.95f / 4096.0f;
    const float C13 = 0.95f / 65536.0f;
    const float FC  = 0.05f / 15.0f;
    float t0 = C15 * s0, t1 = C15 * s1, t2 = C15 * s2, t3 = C15 * s3;
    float t4 = C15 * s4, t5 = C15 * s5, t6 = C15 * s6, t7 = C15 * s7;
#define ADD8T(P, CF)                                                        \
    {                                                                       \
        float4 v = (P)[gi];                                                 \
        DEC8(v, f0, f1, f2, f3)                                             \
        t0 = fmaf((CF), f0.x, t0); t1 = fmaf((CF), f0.y, t1);               \
        t2 = fmaf((CF), f1.x, t2); t3 = fmaf((CF), f1.y, t3);               \
        t4 = fmaf((CF), f2.x, t4); t5 = fmaf((CF), f2.y, t5);               \
        t6 = fmaf((CF), f3.x, t6); t7 = fmaf((CF), f3.y, t7);               \
    }
    ADD8T(x14p, C14)
    ADD8T(x13p, C13)
    ADD8T(z0p, FC)
#undef ADD8T
    float cd = C16 * di;
    float o0 = fmaf(sq, t0, cd * a0), o1 = fmaf(sq, t1, cd * a1);
    float o2 = fmaf(sq, t2, cd * a2), o3 = fmaf(sq, t3, cd * a3);
    float o4 = fmaf(sq, t4, cd * a4), o5 = fmaf(sq, t5, cd * a5);
    float o6 = fmaf(sq, t6, cd * a6), o7 = fmaf(sq, t7, cd * a7);
    const float4* b4 = (const float4*)(bias + p * 8);
    float4 bb0 = b4[0], bb1 = b4[1];
    float4* op = (float4*)(outp + (size_t)g * CC + p * 8);
    op[0] = make_float4(o0 + bb0.x, o1 + bb0.y, o2 + bb0.z, o3 + bb0.w);
    op[1] = make_float4(o4 + bb1.x, o5 + bb1.y, o6 + bb1.z, o7 + bb1.w);
}

__global__ __launch_bounds__(256) void spmm_final(
    const float4* __restrict__ x15, const float4* __restrict__ x13p,
    const float4* __restrict__ x14p, const float4* __restrict__ z0p,
    const float* __restrict__ bias,
    const int* __restrict__ row_ptr, const int* __restrict__ es,
    const float* __restrict__ dinv, const float* __restrict__ sqd,
    float* __restrict__ outp) {
    int xcd = blockIdx.x & 7;
    int slot = blockIdx.x >> 3;
    int t = threadIdx.x;
    if (xcd < 6) {
        int part = (xcd < 3) ? xcd : xcd - 3;
        int grp  = (xcd < 3) ? 0 : 1;
        int b0 = (part == 0) ? 0 : ((part == 1) ? 33334 : 66667);
        int b1 = (part == 0) ? 33334 : ((part == 1) ? 66667 : 100000);
        int g = b0 + slot * 128 + (t >> 1);
        if (g >= b1) return;
        int pl = t & 1;
        final_body<2>(g, pl, grp * 2 + pl, (size_t)grp * 2 * NN,
                      x15, x13p, x14p, z0p, bias, row_ptr, es, dinv, sqd, outp);
    } else {
        if (slot >= SLT4) return;
        int b0 = (xcd - 6) * 50000;
        int g = b0 + slot * 256 + t;
        if (g >= b0 + 50000) return;
        final_body<1>(g, 0, 4, (size_t)4 * NN,
                      x15, x13p, x14p, z0p, bias, row_ptr, es, dinv, sqd, outp);
    }
}

extern "C" void kernel_launch(void* const* d_in, const int* in_sizes, int n_in,
                              void* d_out, int out_size, void* d_ws, size_t ws_size,
                              hipStream_t stream) {
    const float* feat = (const float*)d_in[0];
    const float* W    = (const float*)d_in[1];
    const float* b    = (const float*)d_in[2];
    const int*   src  = (const int*)d_in[3];
    const int*   dst  = (const int*)d_in[4];
    float* out = (float*)d_out;

    char* p = (char*)d_ws;
    auto alloc = [&](size_t bytes) {
        char* r = p;
        p += (bytes + 255) & ~(size_t)255;
        return r;
    };
    float*   dinv    = (float*)alloc((size_t)NN * sizeof(float));
    float*   sqd     = (float*)alloc((size_t)NN * sizeof(float));
    int*     row_ptr = (int*)alloc((size_t)(NN + 1) * sizeof(int));
    int*     cursor  = (int*)alloc((size_t)NBK * sizeof(int));
    int*     bbase   = (int*)alloc((size_t)NBK * sizeof(int));
    int2*    tmp     = (int2*)alloc((size_t)NBK * TCAP * sizeof(int2));  // 12.6MB
    int*     er_src  = (int*)alloc((size_t)EE * sizeof(int));            // 4.8MB
    float4*  z0      = (float4*)alloc((size_t)NN * 5 * sizeof(float4));  // 8MB
    float4*  xa      = (float4*)alloc((size_t)NN * 5 * sizeof(float4));  // 8MB
    float4*  xb      = (float4*)alloc((size_t)NN * 5 * sizeof(float4));  // 8MB
    float4*  z13     = (float4*)alloc((size_t)NN * 5 * sizeof(float4));  // 8MB
    float4*  z14     = (float4*)alloc((size_t)NN * 5 * sizeof(float4));  // 8MB
    float4*  z15     = (float4*)alloc((size_t)NN * 5 * sizeof(float4));  // 8MB

    curinit_kernel<<<1, 512, 0, stream>>>(cursor);
    sortA_kernel<<<ABLK, 256, 0, stream>>>(src, dst, cursor, tmp);
    bscan_kernel<<<1, 512, 0, stream>>>(cursor, bbase, row_ptr);
    sortB_kernel<<<NBK, 256, 0, stream>>>(tmp, cursor, bbase, dinv, sqd, row_ptr, er_src);
    proj_kernel<<<(NN + 63) / 64, 256, 0, stream>>>((const float4*)feat, W, dinv, z0);

    // z1..z12: ping-pong xa/xb
    const float4* xs = z0;
    for (int j = 0; j < 12; ++j) {
        float4* xd = (j & 1) ? xb : xa;
        spmm_prop<<<GRID8, 256, 0, stream>>>(xs, xd, row_ptr, er_src, dinv);
        xs = xd;
    }
    // z13, z14, z15 into preserved buffers
    spmm_prop<<<GRID8, 256, 0, stream>>>(xs, z13, row_ptr, er_src, dinv);
    spmm_prop<<<GRID8, 256, 0, stream>>>(z13, z14, row_ptr, er_src, dinv);
    spmm_prop<<<GRID8, 256, 0, stream>>>(z14, z15, row_ptr, er_src, dinv);
    // final combine
    spmm_final<<<GRID8, 256, 0, stream>>>(z15, z13, z14, z0, b, row_ptr,
                                          er_src, dinv, sqd, out);
}

// Round 5
// 547.796 us; speedup vs baseline: 1.4696x; 1.0913x over previous
//
#include <hip/hip_runtime.h>
#include <hip/hip_fp16.h>

#define NN 100000
#define EE 1200000
#define DD 64
#define CC 40
#define KK 16
#define BSZ 196                          // nodes per sort bucket
#define NBK 512                          // buckets (512*196 = 100352 >= NN)
#define TCAP 3072                        // tmp capacity per bucket (mean 2352, ~15 sigma)
#define EPB 4096                         // edges per phase-A block
#define ABLK ((EE + EPB - 1) / EPB)      // 293

// x layout per state buffer (float4 = 8 halves = 8 channels):
//   P01: [0, 2N)   node n -> {2n, 2n+1};  P23: [2N,4N) same +2N;  P4: [4N,5N) 4N+n
// XCD pinning (block b -> XCD b%8): XCD 0..2 -> planes{0,1} node-thirds,
// 3..5 -> planes{2,3} thirds, 6..7 -> plane{4} halves. Slice/XCD <= 3.2MB.
// Edge-index windows are staged into LDS via bulk nt int4 loads (one pass,
// no L1/L2 footprint); x_out/out stores are nt. => per-XCD L2 holds ONLY the
// gather slice (+row_ptr/dinv) and stays resident across the whole kernel.
#define SLT 261                          // slots/XCD: ceil(33334/128)
#define SLT4 196                         // ceil(50000/256)
#define GRID8 (8 * SLT)                  // 2088 blocks of 256 threads
#define CH 4096                          // staged edge-index window (16KB LDS)

typedef int   v4i __attribute__((ext_vector_type(4)));
typedef float v4f __attribute__((ext_vector_type(4)));

__device__ __forceinline__ v4i ntld_i4(const int* p) {
    return __builtin_nontemporal_load((const v4i*)p);
}
__device__ __forceinline__ float4 ntld_f4(const float4* p) {
    v4f v = __builtin_nontemporal_load((const v4f*)p);
    return make_float4(v.x, v.y, v.z, v.w);
}
__device__ __forceinline__ void ntst_f4(float4* p, float4 f) {
    v4f v; v.x = f.x; v.y = f.y; v.z = f.z; v.w = f.w;
    __builtin_nontemporal_store(v, (v4f*)p);
}

// ---------- cursor init ----------
__global__ __launch_bounds__(512) void curinit_kernel(int* __restrict__ cursor) {
    int b = threadIdx.x;
    if (b < NBK) cursor[b] = b * TCAP;
}

// ---------- sort phase A: LDS-bin 4096 edges into 512 buckets ----------
__global__ __launch_bounds__(256) void sortA_kernel(const int* __restrict__ src,
                                                    const int* __restrict__ dst,
                                                    int* __restrict__ cursor,
                                                    int2* __restrict__ tmp) {
    __shared__ int2 stg[EPB];                 // 32KB
    __shared__ int hist[NBK], loff[NBK], lcur[NBK], gbase[NBK];  // 8KB
    int t = threadIdx.x;
    long e0 = (long)blockIdx.x * EPB;
    int n = (int)((EE - e0 < EPB) ? (EE - e0) : EPB);
    for (int j = t; j < NBK; j += 256) hist[j] = 0;
    __syncthreads();
    int d[16], sx[16];
#pragma unroll
    for (int j = 0; j < 16; ++j) {
        int i = t + j * 256;
        if (i < n) {
            d[j] = dst[e0 + i];
            sx[j] = src[e0 + i];
            atomicAdd(&hist[d[j] / BSZ], 1);
        } else d[j] = -1;
    }
    __syncthreads();
    int c0 = hist[2 * t], c1 = hist[2 * t + 1];
    int s2 = c0 + c1;
    __syncthreads();
    loff[t] = s2;
    __syncthreads();
    for (int off = 1; off < 256; off <<= 1) {
        int u = (t >= off) ? loff[t - off] : 0;
        __syncthreads();
        loff[t] += u;
        __syncthreads();
    }
    int excl = loff[t] - s2;
    __syncthreads();
    loff[2 * t] = excl;          loff[2 * t + 1] = excl + c0;
    lcur[2 * t] = excl;          lcur[2 * t + 1] = excl + c0;
    gbase[2 * t]     = atomicAdd(&cursor[2 * t], c0);
    gbase[2 * t + 1] = atomicAdd(&cursor[2 * t + 1], c1);
    __syncthreads();
#pragma unroll
    for (int j = 0; j < 16; ++j) {
        if (d[j] >= 0) {
            int b = d[j] / BSZ;
            int p = atomicAdd(&lcur[b], 1);
            stg[p] = make_int2(d[j], sx[j]);
        }
    }
    __syncthreads();
    for (int i = t; i < n; i += 256) {
        int2 r = stg[i];
        int b = r.x / BSZ;
        int pos = gbase[b] + (i - loff[b]);
        if (pos < (b + 1) * TCAP) tmp[pos] = r;  // overflow guard (never hit)
    }
}

// ---------- bucket-base scan ----------
__global__ __launch_bounds__(512) void bscan_kernel(const int* __restrict__ cursor,
                                                    int* __restrict__ bbase,
                                                    int* __restrict__ row_ptr) {
    __shared__ int sm[512];
    int t = threadIdx.x;
    int v = (t < NBK) ? (cursor[t] - t * TCAP) : 0;
    sm[t] = v;
    __syncthreads();
    for (int off = 1; off < 512; off <<= 1) {
        int u = (t >= off) ? sm[t - off] : 0;
        __syncthreads();
        sm[t] += u;
        __syncthreads();
    }
    if (t < NBK) bbase[t] = sm[t] - v;
    if (t == 511) row_ptr[NN] = sm[511];  // == EE
}

// ---------- sort phase B: counting sort within bucket; emit src-only edges ----------
__global__ __launch_bounds__(256) void sortB_kernel(const int2* __restrict__ tmp,
                                                    const int* __restrict__ cursor,
                                                    const int* __restrict__ bbase,
                                                    float* __restrict__ dinv,
                                                    float* __restrict__ sqd,
                                                    int* __restrict__ row_ptr,
                                                    int* __restrict__ er_src) {
    __shared__ int2 se[TCAP];     // 24KB
    __shared__ int so[TCAP];      // 12KB (src only)
    __shared__ int hist[256], lcur[256];
    int b = blockIdx.x;
    int n0 = b * BSZ;
    if (n0 >= NN) return;
    int n1 = n0 + BSZ; if (n1 > NN) n1 = NN;
    int nb = n1 - n0;
    int t = threadIdx.x;
    int cnt = cursor[b] - b * TCAP;
    int base = bbase[b];
    hist[t] = 0;
    __syncthreads();
    for (int i = t; i < cnt; i += 256) {
        int2 r = tmp[b * TCAP + i];
        se[i] = r;
        atomicAdd(&hist[r.x - n0], 1);
    }
    __syncthreads();
    if (t < nb) {
        float dg = (float)(hist[t] + 1);   // +1 self-loop
        dinv[n0 + t] = rsqrtf(dg);
        sqd[n0 + t]  = sqrtf(dg);
    }
    int v = hist[t];
    lcur[t] = v;
    __syncthreads();
    for (int off = 1; off < 256; off <<= 1) {
        int u = (t >= off) ? lcur[t - off] : 0;
        __syncthreads();
        lcur[t] += u;
        __syncthreads();
    }
    int excl = lcur[t] - v;
    __syncthreads();
    lcur[t] = excl;
    if (t < nb) row_ptr[n0 + t] = base + excl;
    __syncthreads();
    for (int i = t; i < cnt; i += 256) {
        int2 r = se[i];
        int ln = r.x - n0;
        int pos = atomicAdd(&lcur[ln], 1);
        so[pos] = r.y;                    // src only (z-space: weights folded out)
    }
    __syncthreads();
    for (int i = t; i < cnt; i += 256) er_src[base + i] = so[i];  // coalesced
}

// ---------- projection: z0 = dinv * (feat @ W^T), stored in P-layout ----------
__global__ __launch_bounds__(256) void proj_kernel(const float4* __restrict__ feat4,
                                                   const float* __restrict__ W,
                                                   const float* __restrict__ dinv,
                                                   float4* __restrict__ z0) {
    __shared__ float smW[CC * 68];   // 10.9KB
    __shared__ float smF[64 * 68];   // 17.4KB
    __shared__ float smO[64 * 42];   // 10.8KB
    int t = threadIdx.x;
    for (int j = t; j < CC * 16; j += 256) {
        int c = j >> 4, q = j & 15;
        *(float4*)(smW + c * 68 + q * 4) = ((const float4*)W)[j];
    }
    int n0 = blockIdx.x * 64;
    for (int j = t; j < 64 * 16; j += 256) {
        int r = j >> 4, q = j & 15;
        if (n0 + r < NN)
            *(float4*)(smF + r * 68 + q * 4) = feat4[(size_t)(n0 + r) * 16 + q];
    }
    __syncthreads();
    int ln = t >> 2, c0 = (t & 3) * 10;
    int node = n0 + ln;
    float acc[10];
#pragma unroll
    for (int c = 0; c < 10; ++c) acc[c] = 0.f;
    if (node < NN) {
#pragma unroll
        for (int db = 0; db < 16; ++db) {
            float4 fv = *(const float4*)(smF + ln * 68 + db * 4);
#pragma unroll
            for (int c = 0; c < 10; ++c) {
                float4 wv = *(const float4*)(smW + (c0 + c) * 68 + db * 4);
                acc[c] = fmaf(fv.x, wv.x, acc[c]);
                acc[c] = fmaf(fv.y, wv.y, acc[c]);
                acc[c] = fmaf(fv.z, wv.z, acc[c]);
                acc[c] = fmaf(fv.w, wv.w, acc[c]);
            }
        }
    }
#pragma unroll
    for (int c = 0; c < 10; ++c) smO[ln * 42 + c0 + c] = acc[c];
    __syncthreads();
    for (int j = t; j < 64 * 5; j += 256) {
        int r = j & 63, q = j >> 6;
        int g = n0 + r;
        if (g < NN) {
            float dv = dinv[g];
            const float* s = smO + r * 42 + q * 8;
            float4 ov;
            __half2* op = (__half2*)&ov;
            op[0] = __floats2half2_rn(dv * s[0], dv * s[1]);
            op[1] = __floats2half2_rn(dv * s[2], dv * s[3]);
            op[2] = __floats2half2_rn(dv * s[4], dv * s[5]);
            op[3] = __floats2half2_rn(dv * s[6], dv * s[7]);
            size_t idx = (q < 2) ? ((size_t)g * 2 + q)
                       : (q < 4) ? ((size_t)2 * NN + (size_t)g * 2 + (q - 2))
                                 : ((size_t)4 * NN + g);
            z0[idx] = ov;
        }
    }
}

// decode float4-of-8-halves into 8 floats
#define DEC8(V, F0, F1, F2, F3)                                             \
    const __half2* hp_##F0 = (const __half2*)&(V);                          \
    float2 F0 = __half22float2(hp_##F0[0]), F1 = __half22float2(hp_##F0[1]);\
    float2 F2 = __half22float2(hp_##F0[2]), F3 = __half22float2(hp_##F0[3]);

#define ACC8U(V)                                                            \
    {                                                                       \
        DEC8(V, f0, f1, f2, f3)                                             \
        a0 += f0.x; a1 += f0.y; a2 += f1.x; a3 += f1.y;                     \
        a4 += f2.x; a5 += f2.y; a6 += f3.x; a7 += f3.y;                     \
    }

// gather loop over the LDS-staged edge window [W0,W1), my row clipped to it.
// indices come from LDS (broadcast across sibling lanes); gathers are CACHED
// (the L2-resident slice).
#define GATHER_WINDOW(XP, STR, PL)                                          \
    {                                                                       \
        int lo = (beg > W0) ? beg : W0;                                     \
        int hi = (end < W1) ? end : W1;                                     \
        int e = lo;                                                         \
        for (; e + 8 <= hi; e += 8) {                                       \
            int s0 = sidx[e - A0 + 0], s1 = sidx[e - A0 + 1];               \
            int s2 = sidx[e - A0 + 2], s3 = sidx[e - A0 + 3];               \
            int s4 = sidx[e - A0 + 4], s5 = sidx[e - A0 + 5];               \
            int s6 = sidx[e - A0 + 6], s7 = sidx[e - A0 + 7];               \
            float4 v0 = (XP)[s0 * (STR) + (PL)];                            \
            float4 v1 = (XP)[s1 * (STR) + (PL)];                            \
            float4 v2 = (XP)[s2 * (STR) + (PL)];                            \
            float4 v3 = (XP)[s3 * (STR) + (PL)];                            \
            float4 v4 = (XP)[s4 * (STR) + (PL)];                            \
            float4 v5 = (XP)[s5 * (STR) + (PL)];                            \
            float4 v6 = (XP)[s6 * (STR) + (PL)];                            \
            float4 v7 = (XP)[s7 * (STR) + (PL)];                            \
            ACC8U(v0); ACC8U(v1); ACC8U(v2); ACC8U(v3);                     \
            ACC8U(v4); ACC8U(v5); ACC8U(v6); ACC8U(v7);                     \
        }                                                                   \
        if (e + 4 <= hi) {                                                  \
            int s0 = sidx[e - A0 + 0], s1 = sidx[e - A0 + 1];               \
            int s2 = sidx[e - A0 + 2], s3 = sidx[e - A0 + 3];               \
            float4 v0 = (XP)[s0 * (STR) + (PL)];                            \
            float4 v1 = (XP)[s1 * (STR) + (PL)];                            \
            float4 v2 = (XP)[s2 * (STR) + (PL)];                            \
            float4 v3 = (XP)[s3 * (STR) + (PL)];                            \
            ACC8U(v0); ACC8U(v1); ACC8U(v2); ACC8U(v3);                     \
            e += 4;                                                         \
        }                                                                   \
        for (; e < hi; ++e) {                                               \
            int s = sidx[e - A0];                                           \
            float4 v = (XP)[s * (STR) + (PL)];                              \
            ACC8U(v);                                                       \
        }                                                                   \
    }

// stage es[W0..W1) into LDS with bulk nt int4 loads (no L1/L2 allocation)
#define STAGE_WINDOW                                                        \
    int W1 = (W0 + CH < blkE) ? (W0 + CH) : blkE;                           \
    int A0 = W0 & ~3;                                                       \
    __syncthreads();                                                        \
    for (int i = A0 + (int)threadIdx.x * 4; i < W1; i += 1024) {            \
        *(v4i*)(sidx + (i - A0)) = ntld_i4(es + i);                         \
    }                                                                       \
    __syncthreads();

// ---------- SpMM propagate body: z_out[d] = dinv[d]^2 * (z[d] + sum z[src]) ----------
template <int STR>
__device__ __forceinline__ void prop_body(
    int* sidx, int n0, int n1, int g, bool act, int pl, size_t off,
    const float4* __restrict__ x, float4* __restrict__ x_out,
    const int* __restrict__ row_ptr, const int* __restrict__ es,
    const float* __restrict__ dinv) {
    const float4* xp = x + off;
    int beg = 0, end = 0, sb = 0;
    float w2 = 0.f;
    float a0 = 0, a1 = 0, a2 = 0, a3 = 0, a4 = 0, a5 = 0, a6 = 0, a7 = 0;
    if (act) {
        beg = row_ptr[g]; end = row_ptr[g + 1];
        float di = dinv[g];
        w2 = di * di;
        sb = g * STR + pl;
        float4 sv = xp[sb];
        DEC8(sv, f0, f1, f2, f3)
        a0 = f0.x; a1 = f0.y; a2 = f1.x; a3 = f1.y;
        a4 = f2.x; a5 = f2.y; a6 = f3.x; a7 = f3.y;
    }
    int blkB = row_ptr[n0], blkE = row_ptr[n1];
    for (int W0 = blkB; W0 < blkE; W0 += CH) {
        STAGE_WINDOW
        if (act) GATHER_WINDOW(xp, STR, pl)
    }
    if (act) {
        float4 ov;
        __half2* op = (__half2*)&ov;
        op[0] = __floats2half2_rn(w2 * a0, w2 * a1);
        op[1] = __floats2half2_rn(w2 * a2, w2 * a3);
        op[2] = __floats2half2_rn(w2 * a4, w2 * a5);
        op[3] = __floats2half2_rn(w2 * a6, w2 * a7);
        ntst_f4(x_out + off + sb, ov);   // nt: write-once stream, keep L2 clean
    }
}

__global__ __launch_bounds__(256) void spmm_prop(
    const float4* __restrict__ x, float4* __restrict__ x_out,
    const int* __restrict__ row_ptr, const int* __restrict__ es,
    const float* __restrict__ dinv) {
    __shared__ __align__(16) int sidx[CH + 8];
    int xcd = blockIdx.x & 7;
    int slot = blockIdx.x >> 3;
    int t = threadIdx.x;
    if (xcd < 6) {
        int part = (xcd < 3) ? xcd : xcd - 3;
        int grp  = (xcd < 3) ? 0 : 1;
        int b0 = (part == 0) ? 0 : ((part == 1) ? 33334 : 66667);
        int b1 = (part == 0) ? 33334 : ((part == 1) ? 66667 : 100000);
        int n0 = b0 + slot * 128;
        int n1 = (n0 + 128 < b1) ? (n0 + 128) : b1;
        int g = n0 + (t >> 1);
        prop_body<2>(sidx, n0, n1, g, g < n1, t & 1, (size_t)grp * 2 * NN,
                     x, x_out, row_ptr, es, dinv);
    } else {
        if (slot >= SLT4) return;
        int b0 = (xcd - 6) * 50000;
        int lim = b0 + 50000;
        int n0 = b0 + slot * 256;
        int n1 = (n0 + 256 < lim) ? (n0 + 256) : lim;
        int g = n0 + t;
        prop_body<1>(sidx, n0, n1, g, g < n1, 0, (size_t)4 * NN,
                     x, x_out, row_ptr, es, dinv);
    }
}

// ---------- final: acc = sum z15 (incl self); out = C16*dinv*acc
//            + sqd*(C15*z15 + C14*z14 + C13*z13 + FC*z0) + bias ----------
template <int STR>
__device__ __forceinline__ void final_body(
    int* sidx, int n0, int n1, int g, bool act, int pl, int p, size_t off,
    const float4* __restrict__ x15, const float4* __restrict__ x13p,
    const float4* __restrict__ x14p, const float4* __restrict__ z0p,
    const float* __restrict__ bias,
    const int* __restrict__ row_ptr, const int* __restrict__ es,
    const float* __restrict__ dinv, const float* __restrict__ sqd,
    float* __restrict__ outp) {
    const float4* xp = x15 + off;
    int beg = 0, end = 0, sb = 0;
    float di = 0.f, sq = 0.f;
    float s0 = 0, s1 = 0, s2 = 0, s3 = 0, s4 = 0, s5 = 0, s6 = 0, s7 = 0;
    float a0 = 0, a1 = 0, a2 = 0, a3 = 0, a4 = 0, a5 = 0, a6 = 0, a7 = 0;
    if (act) {
        beg = row_ptr[g]; end = row_ptr[g + 1];
        di = dinv[g];
        sq = sqd[g];
        sb = g * STR + pl;
        float4 sv = xp[sb];
        DEC8(sv, f0, f1, f2, f3)
        s0 = f0.x; s1 = f0.y; s2 = f1.x; s3 = f1.y;
        s4 = f2.x; s5 = f2.y; s6 = f3.x; s7 = f3.y;
        a0 = s0; a1 = s1; a2 = s2; a3 = s3;
        a4 = s4; a5 = s5; a6 = s6; a7 = s7;
    }
    int blkB = row_ptr[n0], blkE = row_ptr[n1];
    for (int W0 = blkB; W0 < blkE; W0 += CH) {
        STAGE_WINDOW
        if (act) GATHER_WINDOW(xp, STR, pl)
    }
    if (!act) return;
    size_t gi = off + sb;
    const float C16 = 0.95f / 16.0f;
    const float C15 = 0.95f / 256.0f;
    const float C14 = 0.95f / 4096.0f;
    const float C13 = 0.95f / 65536.0f;
    const float FC  = 0.05f / 15.0f;
    float t0 = C15 * s0, t1 = C15 * s1, t2 = C15 * s2, t3 = C15 * s3;
    float t4 = C15 * s4, t5 = C15 * s5, t6 = C15 * s6, t7 = C15 * s7;
#define ADD8T(P, CF)                                                        \
    {                                                                       \
        float4 v = ntld_f4((P) + gi);                                       \
        DEC8(v, f0, f1, f2, f3)                                             \
        t0 = fmaf((CF), f0.x, t0); t1 = fmaf((CF), f0.y, t1);               \
        t2 = fmaf((CF), f1.x, t2); t3 = fmaf((CF), f1.y, t3);               \
        t4 = fmaf((CF), f2.x, t4); t5 = fmaf((CF), f2.y, t5);               \
        t6 = fmaf((CF), f3.x, t6); t7 = fmaf((CF), f3.y, t7);               \
    }
    ADD8T(x14p, C14)
    ADD8T(x13p, C13)
    ADD8T(z0p, FC)
#undef ADD8T
    float cd = C16 * di;
    float o0 = fmaf(sq, t0, cd * a0), o1 = fmaf(sq, t1, cd * a1);
    float o2 = fmaf(sq, t2, cd * a2), o3 = fmaf(sq, t3, cd * a3);
    float o4 = fmaf(sq, t4, cd * a4), o5 = fmaf(sq, t5, cd * a5);
    float o6 = fmaf(sq, t6, cd * a6), o7 = fmaf(sq, t7, cd * a7);
    const float4* b4 = (const float4*)(bias + p * 8);
    float4 bb0 = b4[0], bb1 = b4[1];
    float4* op = (float4*)(outp + (size_t)g * CC + p * 8);
    ntst_f4(op,     make_float4(o0 + bb0.x, o1 + bb0.y, o2 + bb0.z, o3 + bb0.w));
    ntst_f4(op + 1, make_float4(o4 + bb1.x, o5 + bb1.y, o6 + bb1.z, o7 + bb1.w));
}

__global__ __launch_bounds__(256) void spmm_final(
    const float4* __restrict__ x15, const float4* __restrict__ x13p,
    const float4* __restrict__ x14p, const float4* __restrict__ z0p,
    const float* __restrict__ bias,
    const int* __restrict__ row_ptr, const int* __restrict__ es,
    const float* __restrict__ dinv, const float* __restrict__ sqd,
    float* __restrict__ outp) {
    __shared__ __align__(16) int sidx[CH + 8];
    int xcd = blockIdx.x & 7;
    int slot = blockIdx.x >> 3;
    int t = threadIdx.x;
    if (xcd < 6) {
        int part = (xcd < 3) ? xcd : xcd - 3;
        int grp  = (xcd < 3) ? 0 : 1;
        int b0 = (part == 0) ? 0 : ((part == 1) ? 33334 : 66667);
        int b1 = (part == 0) ? 33334 : ((part == 1) ? 66667 : 100000);
        int n0 = b0 + slot * 128;
        int n1 = (n0 + 128 < b1) ? (n0 + 128) : b1;
        int g = n0 + (t >> 1);
        int pl = t & 1;
        final_body<2>(sidx, n0, n1, g, g < n1, pl, grp * 2 + pl, (size_t)grp * 2 * NN,
                      x15, x13p, x14p, z0p, bias, row_ptr, es, dinv, sqd, outp);
    } else {
        if (slot >= SLT4) return;
        int b0 = (xcd - 6) * 50000;
        int lim = b0 + 50000;
        int n0 = b0 + slot * 256;
        int n1 = (n0 + 256 < lim) ? (n0 + 256) : lim;
        int g = n0 + t;
        final_body<1>(sidx, n0, n1, g, g < n1, 0, 4, (size_t)4 * NN,
                      x15, x13p, x14p, z0p, bias, row_ptr, es, dinv, sqd, outp);
    }
}

extern "C" void kernel_launch(void* const* d_in, const int* in_sizes, int n_in,
                              void* d_out, int out_size, void* d_ws, size_t ws_size,
                              hipStream_t stream) {
    const float* feat = (const float*)d_in[0];
    const float* W    = (const float*)d_in[1];
    const float* b    = (const float*)d_in[2];
    const int*   src  = (const int*)d_in[3];
    const int*   dst  = (const int*)d_in[4];
    float* out = (float*)d_out;

    char* p = (char*)d_ws;
    auto alloc = [&](size_t bytes) {
        char* r = p;
        p += (bytes + 255) & ~(size_t)255;
        return r;
    };
    float*   dinv    = (float*)alloc((size_t)NN * sizeof(float));
    float*   sqd     = (float*)alloc((size_t)NN * sizeof(float));
    int*     row_ptr = (int*)alloc((size_t)(NN + 1) * sizeof(int));
    int*     cursor  = (int*)alloc((size_t)NBK * sizeof(int));
    int*     bbase   = (int*)alloc((size_t)NBK * sizeof(int));
    int2*    tmp     = (int2*)alloc((size_t)NBK * TCAP * sizeof(int2));  // 12.6MB
    int*     er_src  = (int*)alloc((size_t)EE * sizeof(int) + 64);       // 4.8MB (+pad for int4 tail)
    float4*  z0      = (float4*)alloc((size_t)NN * 5 * sizeof(float4));  // 8MB
    float4*  xa      = (float4*)alloc((size_t)NN * 5 * sizeof(float4));  // 8MB
    float4*  xb      = (float4*)alloc((size_t)NN * 5 * sizeof(float4));  // 8MB
    float4*  z13     = (float4*)alloc((size_t)NN * 5 * sizeof(float4));  // 8MB
    float4*  z14     = (float4*)alloc((size_t)NN * 5 * sizeof(float4));  // 8MB
    float4*  z15     = (float4*)alloc((size_t)NN * 5 * sizeof(float4));  // 8MB

    curinit_kernel<<<1, 512, 0, stream>>>(cursor);
    sortA_kernel<<<ABLK, 256, 0, stream>>>(src, dst, cursor, tmp);
    bscan_kernel<<<1, 512, 0, stream>>>(cursor, bbase, row_ptr);
    sortB_kernel<<<NBK, 256, 0, stream>>>(tmp, cursor, bbase, dinv, sqd, row_ptr, er_src);
    proj_kernel<<<(NN + 63) / 64, 256, 0, stream>>>((const float4*)feat, W, dinv, z0);

    // z1..z12: ping-pong xa/xb
    const float4* xs = z0;
    for (int j = 0; j < 12; ++j) {
        float4* xd = (j & 1) ? xb : xa;
        spmm_prop<<<GRID8, 256, 0, stream>>>(xs, xd, row_ptr, er_src, dinv);
        xs = xd;
    }
    // z13, z14, z15 into preserved buffers
    spmm_prop<<<GRID8, 256, 0, stream>>>(xs, z13, row_ptr, er_src, dinv);
    spmm_prop<<<GRID8, 256, 0, stream>>>(z13, z14, row_ptr, er_src, dinv);
    spmm_prop<<<GRID8, 256, 0, stream>>>(z14, z15, row_ptr, er_src, dinv);
    // final combine
    spmm_final<<<GRID8, 256, 0, stream>>>(z15, z13, z14, z0, b, row_ptr,
                                          er_src, dinv, sqd, out);
}